// Round 14
// baseline (496.073 us; speedup 1.0000x reference)
//
#include <hip/hip_runtime.h>

typedef unsigned short u16;
typedef short s16x8 __attribute__((ext_vector_type(8)));
typedef short s16x4 __attribute__((ext_vector_type(4)));
typedef float f32x4 __attribute__((ext_vector_type(4)));

#define SEQ   2048
#define BATCH 2
#define NHEAD 16

__device__ __forceinline__ float b2f(u16 u) {
    unsigned x = ((unsigned)u) << 16;
    return __builtin_bit_cast(float, x);
}
__device__ __forceinline__ u16 f2b(float f) {
    unsigned x = __builtin_bit_cast(unsigned, f);
    unsigned r = (x + 0x7fffu + ((x >> 16) & 1u)) >> 16;
    return (u16)r;
}
__device__ __forceinline__ s16x8 comb(s16x4 lo, s16x4 hi) {
    return __builtin_shufflevector(lo, hi, 0, 1, 2, 3, 4, 5, 6, 7);
}
__device__ __forceinline__ void gload16(const void* g, void* l) {
    __builtin_amdgcn_global_load_lds(
        (const __attribute__((address_space(1))) void*)g,
        (__attribute__((address_space(3))) void*)l, 16, 0, 0);
}

// ---------------------------------------------------------------------------
// Fused f32->bf16 convert for 4 regions (x, Wqd, Wkvd, Wqu), vec4 granularity.
// ---------------------------------------------------------------------------
__global__ __launch_bounds__(256) void cvt4_k(
    const float* __restrict__ x, const float* __restrict__ wqd,
    const float* __restrict__ wkvd, const float* __restrict__ wqu,
    u16* __restrict__ xb, u16* __restrict__ wqdb,
    u16* __restrict__ wkvdb, u16* __restrict__ wqub)
{
    // region vec4 sizes: x 2097152 | Wqd 786432 | Wkvd 294912 | Wqu 1179648
    const int total = 4358144;
    int i = blockIdx.x * 256 + threadIdx.x;
    const int stride = gridDim.x * 256;
    for (; i < total; i += stride) {
        const float4* src; ushort4* dst; int off;
        if (i < 2097152)      { src = (const float4*)x;    dst = (ushort4*)xb;    off = i; }
        else if (i < 2883584) { src = (const float4*)wqd;  dst = (ushort4*)wqdb;  off = i - 2097152; }
        else if (i < 3178496) { src = (const float4*)wkvd; dst = (ushort4*)wkvdb; off = i - 2883584; }
        else                  { src = (const float4*)wqu;  dst = (ushort4*)wqub;  off = i - 3178496; }
        float4 v = src[off];
        ushort4 o = { f2b(v.x), f2b(v.y), f2b(v.z), f2b(v.w) };
        dst[off] = o;
    }
}

__global__ __launch_bounds__(256) void cvt_bf16_k(
    const float* __restrict__ in, u16* __restrict__ out, int n4)
{
    int i = blockIdx.x * 256 + threadIdx.x;
    const int stride = gridDim.x * 256;
    for (; i < n4; i += stride) {
        float4 v = ((const float4*)in)[i];
        ushort4 o = { f2b(v.x), f2b(v.y), f2b(v.z), f2b(v.w) };
        ((ushort4*)out)[i] = o;
    }
}

// ---------------------------------------------------------------------------
// m97-style MFMA GEMM: C[M,N] = A[M,K](bf16) @ W[N,K](bf16)^T + bias[N](f32)
// ---------------------------------------------------------------------------
template <int OUT_BF16>
__global__ __launch_bounds__(256) void gemm_bf_k(
    const u16* __restrict__ A, const u16* __restrict__ W,
    const float* __restrict__ bias, void* __restrict__ Cout,
    int M, int N, int K, int lda)
{
    __shared__ u16 lsA[128 * 64];
    __shared__ u16 lsB[128 * 64];
    const int tid  = threadIdx.x;
    const int lane = tid & 63;
    const int w    = tid >> 6;
    const int wm   = w >> 1, wn = w & 1;
    const int row0 = blockIdx.y * 128;
    const int col0 = blockIdx.x * 128;
    const int lr8  = lane >> 3;
    const int lc8  = (lane & 7) * 8;

    f32x4 acc[4][4];
#pragma unroll
    for (int i = 0; i < 4; i++)
#pragma unroll
        for (int j = 0; j < 4; j++) acc[i][j] = (f32x4){0.f, 0.f, 0.f, 0.f};

    for (int kt = 0; kt < K; kt += 64) {
#pragma unroll
        for (int t = 0; t < 4; t++) {
            const int r = w * 32 + t * 8;
            gload16(A + (size_t)(row0 + r + lr8) * lda + kt + lc8, &lsA[r * 64]);
            int rw = col0 + r + lr8; if (rw >= N) rw = N - 1;
            gload16(W + (size_t)rw * K + kt + lc8, &lsB[r * 64]);
        }
        __syncthreads();
#pragma unroll
        for (int ks = 0; ks < 2; ks++) {
            const int ko = ks * 32 + (lane >> 4) * 8;
            s16x8 af[4], bfr[4];
#pragma unroll
            for (int i = 0; i < 4; i++) {
                af[i]  = *(const s16x8*)&lsA[(wm * 64 + i * 16 + (lane & 15)) * 64 + ko];
                bfr[i] = *(const s16x8*)&lsB[(wn * 64 + i * 16 + (lane & 15)) * 64 + ko];
            }
#pragma unroll
            for (int mf = 0; mf < 4; mf++)
#pragma unroll
                for (int nf = 0; nf < 4; nf++)
                    acc[mf][nf] = __builtin_amdgcn_mfma_f32_16x16x32_bf16(
                        af[mf], bfr[nf], acc[mf][nf], 0, 0, 0);
        }
        __syncthreads();
    }

    const int rb = row0 + wm * 64 + ((lane >> 4) << 2);
    const int cb = col0 + wn * 64 + (lane & 15);
#pragma unroll
    for (int nf = 0; nf < 4; nf++) {
        const int col = cb + nf * 16;
        if (col < N) {
            const float bv = bias[col];
#pragma unroll
            for (int mf = 0; mf < 4; mf++)
#pragma unroll
                for (int r = 0; r < 4; r++) {
                    const int row = rb + mf * 16 + r;
                    float v = acc[mf][nf][r] + bv;
                    if (OUT_BF16) ((u16*)Cout)[(size_t)row * N + col] = f2b(v);
                    else          ((float*)Cout)[(size_t)row * N + col] = v;
                }
        }
    }
}

// ---------------------------------------------------------------------------
// Merged down-projection GEMM: A = x_bf [4096][2048]; virtual N = 2112.
// cols [0,1536)  : W0 = Wqd  -> C0 = qlat (stride 1536), bias bqd
// cols [1536,2112): W1 = Wkvd -> C1 = kvb (stride 576),  bias bkvd
// Col tiles are 128-wide; 1536 % 128 == 0, so each block is in one matrix.
// ---------------------------------------------------------------------------
__global__ __launch_bounds__(256) void gemm_down_k(
    const u16* __restrict__ A, const u16* __restrict__ W0,
    const u16* __restrict__ W1, const float* __restrict__ b0,
    const float* __restrict__ b1, u16* __restrict__ C0, u16* __restrict__ C1)
{
    __shared__ u16 lsA[128 * 64];
    __shared__ u16 lsB[128 * 64];
    const int tid  = threadIdx.x;
    const int lane = tid & 63;
    const int w    = tid >> 6;
    const int wm   = w >> 1, wn = w & 1;
    const int row0 = blockIdx.y * 128;
    const int col0 = blockIdx.x * 128;
    const int lr8  = lane >> 3;
    const int lc8  = (lane & 7) * 8;
    const bool in1 = (col0 >= 1536);
    const u16* Wm  = in1 ? W1 : W0;
    const int wbase = in1 ? col0 - 1536 : col0;
    const int wmax  = in1 ? 575 : 1535;

    f32x4 acc[4][4];
#pragma unroll
    for (int i = 0; i < 4; i++)
#pragma unroll
        for (int j = 0; j < 4; j++) acc[i][j] = (f32x4){0.f, 0.f, 0.f, 0.f};

    for (int kt = 0; kt < 2048; kt += 64) {
#pragma unroll
        for (int t = 0; t < 4; t++) {
            const int r = w * 32 + t * 8;
            gload16(A + (size_t)(row0 + r + lr8) * 2048 + kt + lc8, &lsA[r * 64]);
            int rw = wbase + r + lr8; if (rw > wmax) rw = wmax;
            gload16(Wm + (size_t)rw * 2048 + kt + lc8, &lsB[r * 64]);
        }
        __syncthreads();
#pragma unroll
        for (int ks = 0; ks < 2; ks++) {
            const int ko = ks * 32 + (lane >> 4) * 8;
            s16x8 af[4], bfr[4];
#pragma unroll
            for (int i = 0; i < 4; i++) {
                af[i]  = *(const s16x8*)&lsA[(wm * 64 + i * 16 + (lane & 15)) * 64 + ko];
                bfr[i] = *(const s16x8*)&lsB[(wn * 64 + i * 16 + (lane & 15)) * 64 + ko];
            }
#pragma unroll
            for (int mf = 0; mf < 4; mf++)
#pragma unroll
                for (int nf = 0; nf < 4; nf++)
                    acc[mf][nf] = __builtin_amdgcn_mfma_f32_16x16x32_bf16(
                        af[mf], bfr[nf], acc[mf][nf], 0, 0, 0);
        }
        __syncthreads();
    }

    const int rb = row0 + wm * 64 + ((lane >> 4) << 2);
    const int cb = col0 + wn * 64 + (lane & 15);
#pragma unroll
    for (int nf = 0; nf < 4; nf++) {
        const int col = cb + nf * 16;
        if (col < 2112) {
            const bool c1 = (col >= 1536);
            const float bv = c1 ? b1[col - 1536] : b0[col];
#pragma unroll
            for (int mf = 0; mf < 4; mf++)
#pragma unroll
                for (int r = 0; r < 4; r++) {
                    const int row = rb + mf * 16 + r;
                    float v = acc[mf][nf][r] + bv;
                    if (c1) C1[(size_t)row * 576 + col - 1536] = f2b(v);
                    else    C0[(size_t)row * 1536 + col] = f2b(v);
                }
        }
    }
}

// ---------------------------------------------------------------------------
// In-place RMSNorm on bf16 rows
// ---------------------------------------------------------------------------
__global__ __launch_bounds__(256) void rmsnorm_ip_k(
    u16* __restrict__ buf, const float* __restrict__ w, int cols, int stride)
{
    const int row = blockIdx.x;
    u16* xr = buf + (size_t)row * stride;
    float ss = 0.f;
    for (int c = threadIdx.x; c < cols; c += 256) { float v = b2f(xr[c]); ss += v * v; }
#pragma unroll
    for (int off = 32; off; off >>= 1) ss += __shfl_xor(ss, off);
    __shared__ float red[4];
    if ((threadIdx.x & 63) == 0) red[threadIdx.x >> 6] = ss;
    __syncthreads();
    const float tot = red[0] + red[1] + red[2] + red[3];
    const float inv = rsqrtf(tot / (float)cols + 1.1920929e-7f);
    for (int c = threadIdx.x; c < cols; c += 256)
        xr[c] = f2b(b2f(xr[c]) * inv * w[c]);
}

// ---------------------------------------------------------------------------
// RoPE kernels
// ---------------------------------------------------------------------------
__global__ __launch_bounds__(256) void rope_q_k(
    u16* __restrict__ qb, const float* __restrict__ fc, const float* __restrict__ fs)
{
    const int idx = blockIdx.x * 256 + threadIdx.x;
    const int i = idx & 31;
    const int h = (idx >> 5) & 15;
    const int row = idx >> 9;
    const int s = row & (SEQ - 1);
    ushort2* p = (ushort2*)(qb + (size_t)row * 3072 + h * 192 + 128) + i;
    ushort2 v = *p;
    const float xr = b2f(v.x), xi = b2f(v.y);
    const float c = fc[s * 32 + i], sn = fs[s * 32 + i];
    ushort2 o;
    o.x = f2b(xr * c - xi * sn);
    o.y = f2b(xr * sn + xi * c);
    *p = o;
}

__global__ __launch_bounds__(256) void rope_k_k(
    const u16* __restrict__ kvb, const float* __restrict__ fc,
    const float* __restrict__ fs, u16* __restrict__ krope)
{
    const int idx = blockIdx.x * 256 + threadIdx.x;
    const int i = idx & 31;
    const int row = idx >> 5;
    const int s = row & (SEQ - 1);
    const u16* src = kvb + (size_t)row * 576 + 512 + 2 * i;
    const float xr = b2f(src[0]), xi = b2f(src[1]);
    const float c = fc[s * 32 + i], sn = fs[s * 32 + i];
    ushort2 o;
    o.x = f2b(xr * c - xi * sn);
    o.y = f2b(xr * sn + xi * c);
    *((ushort2*)(krope + (size_t)row * 64) + i) = o;
}

// ---------------------------------------------------------------------------
// MFMA flash attention v4: persistent blocks + atomic work queue.
// Work item = (b, h, 128-row q-tile), 512 items, heavy (large qt) first.
// Per item: 4 waves x 32 rows (2 m-frags); KVBLK=64; register prefetch.
// ---------------------------------------------------------------------------
__global__ __launch_bounds__(256, 2) void attn_k(
    const u16* __restrict__ Q, const u16* __restrict__ KNV,
    const u16* __restrict__ KR, u16* __restrict__ O, unsigned* __restrict__ ctr)
{
    __shared__ u16 k_lds[64][200];
    __shared__ u16 v_t[128][68];
    __shared__ u16 p_lds[4][32][68];
    __shared__ int item_s;

    const int tid  = threadIdx.x;
    const int lane = tid & 63;
    const int w    = tid >> 6;
    const int lr   = lane & 15;
    const int lq   = lane >> 4;
    const float scale = 0.07216878364870323f;  // 192^-0.5

    const int kkey = tid >> 2;
    const int ka   = tid & 3;

    while (true) {
        if (tid == 0) item_s = (int)atomicAdd(ctr, 1u);
        __syncthreads();
        const int item = item_s;
        __syncthreads();               // item read before next overwrite
        if (item >= 512) return;

        const int qt = 15 - (item >> 5);   // heavy first
        const int bh = item & 31;
        const int h  = bh & 15;
        const int b  = bh >> 4;
        const int q0 = qt * 128;
        const int bS = b * SEQ;

        // Q fragments: 2 m-blocks x 6 k-chunks
        s16x8 qf[2][6];
#pragma unroll
        for (int mb = 0; mb < 2; mb++) {
            const u16* qp = Q + (size_t)(bS + q0 + w * 32 + mb * 16 + lr) * 3072
                            + h * 192 + (lq << 2);
#pragma unroll
            for (int kc = 0; kc < 6; kc++)
                qf[mb][kc] = comb(*(const s16x4*)(qp + kc * 32),
                                  *(const s16x4*)(qp + kc * 32 + 16));
        }

        f32x4 o_acc[2][8];
#pragma unroll
        for (int mb = 0; mb < 2; mb++)
#pragma unroll
            for (int d = 0; d < 8; d++) o_acc[mb][d] = (f32x4){0.f, 0.f, 0.f, 0.f};
        float m[2][4], l[2][4];
#pragma unroll
        for (int mb = 0; mb < 2; mb++)
#pragma unroll
            for (int r = 0; r < 4; r++) { m[mb][r] = -1e30f; l[mb][r] = 0.f; }

        const int ntiles = (q0 + 128) / 64;

        s16x8 kr[6], vr[4];
        {
            const u16* kn  = KNV + (size_t)(bS + kkey) * 4096 + h * 256;
            const u16* krp = KR + (size_t)(bS + kkey) * 64;
#pragma unroll
            for (int i = 0; i < 6; i++) {
                const int col = ka * 48 + i * 8;
                kr[i] = *(const s16x8*)(col < 128 ? kn + col : krp + (col - 128));
            }
#pragma unroll
            for (int i = 0; i < 4; i++) {
                const int idx = tid + i * 256;
                vr[i] = *(const s16x8*)(KNV + (size_t)(bS + (idx >> 4)) * 4096
                                        + h * 256 + 128 + (idx & 15) * 8);
            }
        }

        for (int t = 0; t < ntiles; t++) {
#pragma unroll
            for (int i = 0; i < 6; i++)
                *(s16x8*)&k_lds[kkey][ka * 48 + i * 8] = kr[i];
#pragma unroll
            for (int i = 0; i < 4; i++) {
                const int idx = tid + i * 256;
                const int key = idx >> 4, d0 = (idx & 15) * 8;
                const int xw = (d0 >> 4) << 2;
#pragma unroll
                for (int e = 0; e < 8; e++) v_t[d0 + e][key ^ xw] = (u16)vr[i][e];
            }
            __syncthreads();

            if (t + 1 < ntiles) {
                const int nk = (t + 1) * 64;
                const u16* kn  = KNV + (size_t)(bS + nk + kkey) * 4096 + h * 256;
                const u16* krp = KR + (size_t)(bS + nk + kkey) * 64;
#pragma unroll
                for (int i = 0; i < 6; i++) {
                    const int col = ka * 48 + i * 8;
                    kr[i] = *(const s16x8*)(col < 128 ? kn + col : krp + (col - 128));
                }
#pragma unroll
                for (int i = 0; i < 4; i++) {
                    const int idx = tid + i * 256;
                    vr[i] = *(const s16x8*)(KNV + (size_t)(bS + nk + (idx >> 4)) * 4096
                                            + h * 256 + 128 + (idx & 15) * 8);
                }
            }

            const int kt0 = t * 64;

            f32x4 sa[2][4];
#pragma unroll
            for (int mb = 0; mb < 2; mb++)
#pragma unroll
                for (int f = 0; f < 4; f++) sa[mb][f] = (f32x4){0.f, 0.f, 0.f, 0.f};
#pragma unroll
            for (int kc = 0; kc < 6; kc++) {
                const int kb = kc * 32 + (lq << 2);
#pragma unroll
                for (int f = 0; f < 4; f++) {
                    s16x8 kf = comb(*(const s16x4*)&k_lds[f * 16 + lr][kb],
                                    *(const s16x4*)&k_lds[f * 16 + lr][kb + 16]);
                    sa[0][f] = __builtin_amdgcn_mfma_f32_16x16x32_bf16(qf[0][kc], kf, sa[0][f], 0, 0, 0);
                    sa[1][f] = __builtin_amdgcn_mfma_f32_16x16x32_bf16(qf[1][kc], kf, sa[1][f], 0, 0, 0);
                }
            }

#pragma unroll
            for (int mb = 0; mb < 2; mb++) {
                const int qbase = q0 + w * 32 + mb * 16 + lq * 4;
                const bool need_mask = (kt0 + 63 > qbase);
                float p[4][4];
#pragma unroll
                for (int f = 0; f < 4; f++)
#pragma unroll
                    for (int r = 0; r < 4; r++) {
                        float s = sa[mb][f][r] * scale;
                        if (need_mask && (kt0 + f * 16 + lr > qbase + r)) s = -1e30f;
                        p[f][r] = s;
                    }
                float nm[4], corr[4];
#pragma unroll
                for (int r = 0; r < 4; r++) {
                    float tm = fmaxf(fmaxf(p[0][r], p[1][r]), fmaxf(p[2][r], p[3][r]));
#pragma unroll
                    for (int off = 8; off; off >>= 1) tm = fmaxf(tm, __shfl_xor(tm, off));
                    nm[r] = fmaxf(m[mb][r], tm);
                    corr[r] = __expf(m[mb][r] - nm[r]);
                    m[mb][r] = nm[r];
                }
#pragma unroll
                for (int f = 0; f < 4; f++)
#pragma unroll
                    for (int r = 0; r < 4; r++)
                        p[f][r] = __expf(p[f][r] - nm[r]);
#pragma unroll
                for (int r = 0; r < 4; r++) {
                    float ps = (p[0][r] + p[1][r]) + (p[2][r] + p[3][r]);
#pragma unroll
                    for (int off = 8; off; off >>= 1) ps += __shfl_xor(ps, off);
                    l[mb][r] = l[mb][r] * corr[r] + ps;
                }
#pragma unroll
                for (int d = 0; d < 8; d++)
#pragma unroll
                    for (int r = 0; r < 4; r++) o_acc[mb][d][r] *= corr[r];
#pragma unroll
                for (int f = 0; f < 4; f++)
#pragma unroll
                    for (int r = 0; r < 4; r++)
                        p_lds[w][mb * 16 + lq * 4 + r][f * 16 + lr] = f2b(p[f][r]);
            }
            asm volatile("s_waitcnt lgkmcnt(0)" ::: "memory");

#pragma unroll
            for (int hf = 0; hf < 2; hf++) {
                const int pc = hf * 32 + (lq << 2);
                s16x8 pa0 = comb(*(const s16x4*)&p_lds[w][lr][pc],
                                 *(const s16x4*)&p_lds[w][lr][pc + 16]);
                s16x8 pa1 = comb(*(const s16x4*)&p_lds[w][16 + lr][pc],
                                 *(const s16x4*)&p_lds[w][16 + lr][pc + 16]);
#pragma unroll
                for (int d = 0; d < 8; d++) {
                    const int row = d * 16 + lr;
                    const int xr0 = d << 2;
                    s16x8 vf = comb(*(const s16x4*)&v_t[row][pc ^ xr0],
                                    *(const s16x4*)&v_t[row][(pc + 16) ^ xr0]);
                    o_acc[0][d] = __builtin_amdgcn_mfma_f32_16x16x32_bf16(pa0, vf, o_acc[0][d], 0, 0, 0);
                    o_acc[1][d] = __builtin_amdgcn_mfma_f32_16x16x32_bf16(pa1, vf, o_acc[1][d], 0, 0, 0);
                }
            }
            __syncthreads();
        }

        // epilogue for this item
#pragma unroll
        for (int mb = 0; mb < 2; mb++) {
            float invl[4];
#pragma unroll
            for (int r = 0; r < 4; r++) invl[r] = 1.f / l[mb][r];
#pragma unroll
            for (int r = 0; r < 4; r++) {
                u16* op = O + (size_t)(bS + q0 + w * 32 + mb * 16 + lq * 4 + r) * 2048
                          + h * 128 + lr;
#pragma unroll
                for (int d = 0; d < 8; d++)
                    op[d * 16] = f2b(o_acc[mb][d][r] * invl[r]);
            }
        }
        __syncthreads();   // protect LDS before next item's staging
    }
}

// ---------------------------------------------------------------------------
extern "C" void kernel_launch(void* const* d_in, const int* in_sizes, int n_in,
                              void* d_out, int out_size, void* d_ws, size_t ws_size,
                              hipStream_t stream)
{
    const float* x    = (const float*)d_in[0];
    const float* fc   = (const float*)d_in[1];
    const float* fs   = (const float*)d_in[2];
    const float* Wqd  = (const float*)d_in[3];
    const float* bqd  = (const float*)d_in[4];
    const float* qnw  = (const float*)d_in[5];
    const float* Wqu  = (const float*)d_in[6];
    const float* bqu  = (const float*)d_in[7];
    const float* Wkvd = (const float*)d_in[8];
    const float* bkvd = (const float*)d_in[9];
    const float* kvnw = (const float*)d_in[10];
    const float* Wkvu = (const float*)d_in[11];
    const float* bkvu = (const float*)d_in[12];
    const float* Wo   = (const float*)d_in[13];
    const float* bo   = (const float*)d_in[14];

    char* ws = (char*)d_ws;
    u16* kvb     = (u16*)(ws);                 // [4096][576]
    u16* qlat    = (u16*)(ws + 4718592);       // [4096][1536]
    u16* qbuf    = (u16*)(ws + 17301504);      // [4096][3072]
    u16* krope   = (u16*)(ws + 42467328);      // [4096][64]
    u16* knv     = (u16*)(ws + 42991616);      // [4096][4096] (ends 76546048)
    u16* attn_o  = (u16*)(ws);                 // [4096][2048] reuses kvb+qlat
    u16* x_bf    = (u16*)(ws + 17301504);      // in qbuf slot (dead before qup)
    u16* wqd_bf  = (u16*)(ws + 42991616);      // in knv slot (dead before kvup)
    u16* wkvd_bf = (u16*)(ws + 49283072);
    u16* wqu_bf  = (u16*)(ws + 51642368);
    u16* wkvu_bf = (u16*)(ws + 4718592);       // in qlat slot (qlat dead by then)
    u16* wo_bf   = (u16*)(ws + 42991616);      // in knv slot (knv dead after attn)
    unsigned* ctr = (unsigned*)(ws + 76546048); // 4B work-queue counter

    const int M = BATCH * SEQ;  // 4096

    hipMemsetAsync(ctr, 0, 4, stream);
    cvt4_k<<<2048, 256, 0, stream>>>(x, Wqd, Wkvd, Wqu, x_bf, wqd_bf, wkvd_bf, wqu_bf);

    // merged down-proj (qlat + kvb in one GEMM, N=2112)
    gemm_down_k<<<dim3(17, 32), 256, 0, stream>>>(x_bf, wqd_bf, wkvd_bf, bqd, bkvd, qlat, kvb);
    rmsnorm_ip_k<<<M, 256, 0, stream>>>(qlat, qnw, 1536, 1536);
    rmsnorm_ip_k<<<M, 256, 0, stream>>>(kvb, kvnw, 512, 576);
    rope_k_k<<<(M * 32) / 256, 256, 0, stream>>>(kvb, fc, fs, krope);
    gemm_bf_k<1><<<dim3(24, 32), 256, 0, stream>>>(qlat, wqu_bf, bqu, qbuf, M, 3072, 1536, 1536);
    rope_q_k<<<(M * 16 * 32) / 256, 256, 0, stream>>>(qbuf, fc, fs);
    cvt_bf16_k<<<1024, 256, 0, stream>>>(Wkvu, wkvu_bf, 2097152 / 4);
    gemm_bf_k<1><<<dim3(32, 32), 256, 0, stream>>>(kvb, wkvu_bf, bkvu, knv, M, 4096, 512, 576);
    attn_k<<<512, 256, 0, stream>>>(qbuf, knv, krope, attn_o, ctr);
    cvt_bf16_k<<<1024, 256, 0, stream>>>(Wo, wo_bf, 4194304 / 4);
    gemm_bf_k<0><<<dim3(16, 32), 256, 0, stream>>>(attn_o, wo_bf, bo, (float*)d_out, M, 2048, 2048, 2048);
}

// Round 15
// 470.713 us; speedup vs baseline: 1.0539x; 1.0539x over previous
//
#include <hip/hip_runtime.h>

typedef unsigned short u16;
typedef short s16x8 __attribute__((ext_vector_type(8)));
typedef short s16x4 __attribute__((ext_vector_type(4)));
typedef float f32x4 __attribute__((ext_vector_type(4)));

#define SEQ   2048
#define BATCH 2
#define NHEAD 16

__device__ __forceinline__ float b2f(u16 u) {
    unsigned x = ((unsigned)u) << 16;
    return __builtin_bit_cast(float, x);
}
__device__ __forceinline__ u16 f2b(float f) {
    unsigned x = __builtin_bit_cast(unsigned, f);
    unsigned r = (x + 0x7fffu + ((x >> 16) & 1u)) >> 16;
    return (u16)r;
}
__device__ __forceinline__ s16x8 comb(s16x4 lo, s16x4 hi) {
    return __builtin_shufflevector(lo, hi, 0, 1, 2, 3, 4, 5, 6, 7);
}
__device__ __forceinline__ void gload16(const void* g, void* l) {
    __builtin_amdgcn_global_load_lds(
        (const __attribute__((address_space(1))) void*)g,
        (__attribute__((address_space(3))) void*)l, 16, 0, 0);
}

// ---------------------------------------------------------------------------
// Fused f32->bf16 convert for 4 regions (x, Wqd, Wkvd, Wqu).
// ---------------------------------------------------------------------------
__global__ __launch_bounds__(256) void cvt4_k(
    const float* __restrict__ x, const float* __restrict__ wqd,
    const float* __restrict__ wkvd, const float* __restrict__ wqu,
    u16* __restrict__ xb, u16* __restrict__ wqdb,
    u16* __restrict__ wkvdb, u16* __restrict__ wqub)
{
    const int total = 4358144;
    int i = blockIdx.x * 256 + threadIdx.x;
    const int stride = gridDim.x * 256;
    for (; i < total; i += stride) {
        const float4* src; ushort4* dst; int off;
        if (i < 2097152)      { src = (const float4*)x;    dst = (ushort4*)xb;    off = i; }
        else if (i < 2883584) { src = (const float4*)wqd;  dst = (ushort4*)wqdb;  off = i - 2097152; }
        else if (i < 3178496) { src = (const float4*)wkvd; dst = (ushort4*)wkvdb; off = i - 2883584; }
        else                  { src = (const float4*)wqu;  dst = (ushort4*)wqub;  off = i - 3178496; }
        float4 v = src[off];
        ushort4 o = { f2b(v.x), f2b(v.y), f2b(v.z), f2b(v.w) };
        dst[off] = o;
    }
}

__global__ __launch_bounds__(256) void cvt_bf16_k(
    const float* __restrict__ in, u16* __restrict__ out, int n4)
{
    int i = blockIdx.x * 256 + threadIdx.x;
    const int stride = gridDim.x * 256;
    for (; i < n4; i += stride) {
        float4 v = ((const float4*)in)[i];
        ushort4 o = { f2b(v.x), f2b(v.y), f2b(v.z), f2b(v.w) };
        ((ushort4*)out)[i] = o;
    }
}

// ---------------------------------------------------------------------------
// m97-style MFMA GEMM: C[M,N] = A[M,K](bf16) @ W[N,K](bf16)^T + bias[N](f32)
// ---------------------------------------------------------------------------
template <int OUT_BF16>
__global__ __launch_bounds__(256) void gemm_bf_k(
    const u16* __restrict__ A, const u16* __restrict__ W,
    const float* __restrict__ bias, void* __restrict__ Cout,
    int M, int N, int K, int lda)
{
    __shared__ u16 lsA[128 * 64];
    __shared__ u16 lsB[128 * 64];
    const int tid  = threadIdx.x;
    const int lane = tid & 63;
    const int w    = tid >> 6;
    const int wm   = w >> 1, wn = w & 1;
    const int row0 = blockIdx.y * 128;
    const int col0 = blockIdx.x * 128;
    const int lr8  = lane >> 3;
    const int lc8  = (lane & 7) * 8;

    f32x4 acc[4][4];
#pragma unroll
    for (int i = 0; i < 4; i++)
#pragma unroll
        for (int j = 0; j < 4; j++) acc[i][j] = (f32x4){0.f, 0.f, 0.f, 0.f};

    for (int kt = 0; kt < K; kt += 64) {
#pragma unroll
        for (int t = 0; t < 4; t++) {
            const int r = w * 32 + t * 8;
            gload16(A + (size_t)(row0 + r + lr8) * lda + kt + lc8, &lsA[r * 64]);
            int rw = col0 + r + lr8; if (rw >= N) rw = N - 1;
            gload16(W + (size_t)rw * K + kt + lc8, &lsB[r * 64]);
        }
        __syncthreads();
#pragma unroll
        for (int ks = 0; ks < 2; ks++) {
            const int ko = ks * 32 + (lane >> 4) * 8;
            s16x8 af[4], bfr[4];
#pragma unroll
            for (int i = 0; i < 4; i++) {
                af[i]  = *(const s16x8*)&lsA[(wm * 64 + i * 16 + (lane & 15)) * 64 + ko];
                bfr[i] = *(const s16x8*)&lsB[(wn * 64 + i * 16 + (lane & 15)) * 64 + ko];
            }
#pragma unroll
            for (int mf = 0; mf < 4; mf++)
#pragma unroll
                for (int nf = 0; nf < 4; nf++)
                    acc[mf][nf] = __builtin_amdgcn_mfma_f32_16x16x32_bf16(
                        af[mf], bfr[nf], acc[mf][nf], 0, 0, 0);
        }
        __syncthreads();
    }

    const int rb = row0 + wm * 64 + ((lane >> 4) << 2);
    const int cb = col0 + wn * 64 + (lane & 15);
#pragma unroll
    for (int nf = 0; nf < 4; nf++) {
        const int col = cb + nf * 16;
        if (col < N) {
            const float bv = bias[col];
#pragma unroll
            for (int mf = 0; mf < 4; mf++)
#pragma unroll
                for (int r = 0; r < 4; r++) {
                    const int row = rb + mf * 16 + r;
                    float v = acc[mf][nf][r] + bv;
                    if (OUT_BF16) ((u16*)Cout)[(size_t)row * N + col] = f2b(v);
                    else          ((float*)Cout)[(size_t)row * N + col] = v;
                }
        }
    }
}

// ---------------------------------------------------------------------------
// Merged down-projection GEMM (virtual N = 2112: qlat cols + kvb cols).
// ---------------------------------------------------------------------------
__global__ __launch_bounds__(256) void gemm_down_k(
    const u16* __restrict__ A, const u16* __restrict__ W0,
    const u16* __restrict__ W1, const float* __restrict__ b0,
    const float* __restrict__ b1, u16* __restrict__ C0, u16* __restrict__ C1)
{
    __shared__ u16 lsA[128 * 64];
    __shared__ u16 lsB[128 * 64];
    const int tid  = threadIdx.x;
    const int lane = tid & 63;
    const int w    = tid >> 6;
    const int wm   = w >> 1, wn = w & 1;
    const int row0 = blockIdx.y * 128;
    const int col0 = blockIdx.x * 128;
    const int lr8  = lane >> 3;
    const int lc8  = (lane & 7) * 8;
    const bool in1 = (col0 >= 1536);
    const u16* Wm  = in1 ? W1 : W0;
    const int wbase = in1 ? col0 - 1536 : col0;
    const int wmax  = in1 ? 575 : 1535;

    f32x4 acc[4][4];
#pragma unroll
    for (int i = 0; i < 4; i++)
#pragma unroll
        for (int j = 0; j < 4; j++) acc[i][j] = (f32x4){0.f, 0.f, 0.f, 0.f};

    for (int kt = 0; kt < 2048; kt += 64) {
#pragma unroll
        for (int t = 0; t < 4; t++) {
            const int r = w * 32 + t * 8;
            gload16(A + (size_t)(row0 + r + lr8) * 2048 + kt + lc8, &lsA[r * 64]);
            int rw = wbase + r + lr8; if (rw > wmax) rw = wmax;
            gload16(Wm + (size_t)rw * 2048 + kt + lc8, &lsB[r * 64]);
        }
        __syncthreads();
#pragma unroll
        for (int ks = 0; ks < 2; ks++) {
            const int ko = ks * 32 + (lane >> 4) * 8;
            s16x8 af[4], bfr[4];
#pragma unroll
            for (int i = 0; i < 4; i++) {
                af[i]  = *(const s16x8*)&lsA[(wm * 64 + i * 16 + (lane & 15)) * 64 + ko];
                bfr[i] = *(const s16x8*)&lsB[(wn * 64 + i * 16 + (lane & 15)) * 64 + ko];
            }
#pragma unroll
            for (int mf = 0; mf < 4; mf++)
#pragma unroll
                for (int nf = 0; nf < 4; nf++)
                    acc[mf][nf] = __builtin_amdgcn_mfma_f32_16x16x32_bf16(
                        af[mf], bfr[nf], acc[mf][nf], 0, 0, 0);
        }
        __syncthreads();
    }

    const int rb = row0 + wm * 64 + ((lane >> 4) << 2);
    const int cb = col0 + wn * 64 + (lane & 15);
#pragma unroll
    for (int nf = 0; nf < 4; nf++) {
        const int col = cb + nf * 16;
        if (col < 2112) {
            const bool c1 = (col >= 1536);
            const float bv = c1 ? b1[col - 1536] : b0[col];
#pragma unroll
            for (int mf = 0; mf < 4; mf++)
#pragma unroll
                for (int r = 0; r < 4; r++) {
                    const int row = rb + mf * 16 + r;
                    float v = acc[mf][nf][r] + bv;
                    if (c1) C1[(size_t)row * 576 + col - 1536] = f2b(v);
                    else    C0[(size_t)row * 1536 + col] = f2b(v);
                }
        }
    }
}

// ---------------------------------------------------------------------------
// In-place RMSNorm on bf16 rows
// ---------------------------------------------------------------------------
__global__ __launch_bounds__(256) void rmsnorm_ip_k(
    u16* __restrict__ buf, const float* __restrict__ w, int cols, int stride)
{
    const int row = blockIdx.x;
    u16* xr = buf + (size_t)row * stride;
    float ss = 0.f;
    for (int c = threadIdx.x; c < cols; c += 256) { float v = b2f(xr[c]); ss += v * v; }
#pragma unroll
    for (int off = 32; off; off >>= 1) ss += __shfl_xor(ss, off);
    __shared__ float red[4];
    if ((threadIdx.x & 63) == 0) red[threadIdx.x >> 6] = ss;
    __syncthreads();
    const float tot = red[0] + red[1] + red[2] + red[3];
    const float inv = rsqrtf(tot / (float)cols + 1.1920929e-7f);
    for (int c = threadIdx.x; c < cols; c += 256)
        xr[c] = f2b(b2f(xr[c]) * inv * w[c]);
}

// ---------------------------------------------------------------------------
// RoPE kernels
// ---------------------------------------------------------------------------
__global__ __launch_bounds__(256) void rope_q_k(
    u16* __restrict__ qb, const float* __restrict__ fc, const float* __restrict__ fs)
{
    const int idx = blockIdx.x * 256 + threadIdx.x;
    const int i = idx & 31;
    const int h = (idx >> 5) & 15;
    const int row = idx >> 9;
    const int s = row & (SEQ - 1);
    ushort2* p = (ushort2*)(qb + (size_t)row * 3072 + h * 192 + 128) + i;
    ushort2 v = *p;
    const float xr = b2f(v.x), xi = b2f(v.y);
    const float c = fc[s * 32 + i], sn = fs[s * 32 + i];
    ushort2 o;
    o.x = f2b(xr * c - xi * sn);
    o.y = f2b(xr * sn + xi * c);
    *p = o;
}

__global__ __launch_bounds__(256) void rope_k_k(
    const u16* __restrict__ kvb, const float* __restrict__ fc,
    const float* __restrict__ fs, u16* __restrict__ krope)
{
    const int idx = blockIdx.x * 256 + threadIdx.x;
    const int i = idx & 31;
    const int row = idx >> 5;
    const int s = row & (SEQ - 1);
    const u16* src = kvb + (size_t)row * 576 + 512 + 2 * i;
    const float xr = b2f(src[0]), xi = b2f(src[1]);
    const float c = fc[s * 32 + i], sn = fs[s * 32 + i];
    ushort2 o;
    o.x = f2b(xr * c - xi * sn);
    o.y = f2b(xr * sn + xi * c);
    *((ushort2*)(krope + (size_t)row * 64) + i) = o;
}

// ---------------------------------------------------------------------------
// MFMA flash attention v5: static grid, CU-paired causal balancing.
// bid<256 -> heavy tiles qt=15..8; bid>=256 -> light tiles qt=0..7.
// Co-resident pair (bid, bid+256) sums to 34 K-tile units on every CU
// (dispatch-order heuristic; affects speed only, not correctness).
// 4 waves x 32 rows (2 m-frags); KVBLK=64; register prefetch (T14).
// ---------------------------------------------------------------------------
__global__ __launch_bounds__(256, 2) void attn_k(
    const u16* __restrict__ Q, const u16* __restrict__ KNV,
    const u16* __restrict__ KR, u16* __restrict__ O)
{
    __shared__ u16 k_lds[64][200];
    __shared__ u16 v_t[128][68];
    __shared__ u16 p_lds[4][32][68];

    const int tid  = threadIdx.x;
    const int lane = tid & 63;
    const int w    = tid >> 6;
    const int lr   = lane & 15;
    const int lq   = lane >> 4;

    const int bid = blockIdx.x;
    const int qt  = (bid < 256) ? (15 - (bid >> 5)) : ((bid - 256) >> 5);
    const int bh  = bid & 31;
    const int h   = bh & 15;
    const int b   = bh >> 4;
    const int q0  = qt * 128;
    const int bS  = b * SEQ;

    s16x8 qf[2][6];
#pragma unroll
    for (int mb = 0; mb < 2; mb++) {
        const u16* qp = Q + (size_t)(bS + q0 + w * 32 + mb * 16 + lr) * 3072
                        + h * 192 + (lq << 2);
#pragma unroll
        for (int kc = 0; kc < 6; kc++)
            qf[mb][kc] = comb(*(const s16x4*)(qp + kc * 32),
                              *(const s16x4*)(qp + kc * 32 + 16));
    }

    f32x4 o_acc[2][8];
#pragma unroll
    for (int mb = 0; mb < 2; mb++)
#pragma unroll
        for (int d = 0; d < 8; d++) o_acc[mb][d] = (f32x4){0.f, 0.f, 0.f, 0.f};
    float m[2][4], l[2][4];
#pragma unroll
    for (int mb = 0; mb < 2; mb++)
#pragma unroll
        for (int r = 0; r < 4; r++) { m[mb][r] = -1e30f; l[mb][r] = 0.f; }

    const float scale = 0.07216878364870323f;  // 192^-0.5
    const int ntiles = (q0 + 128) / 64;

    s16x8 kr[6], vr[4];
    const int kkey = tid >> 2;
    const int ka   = tid & 3;

    {
        const u16* kn  = KNV + (size_t)(bS + kkey) * 4096 + h * 256;
        const u16* krp = KR + (size_t)(bS + kkey) * 64;
#pragma unroll
        for (int i = 0; i < 6; i++) {
            const int col = ka * 48 + i * 8;
            kr[i] = *(const s16x8*)(col < 128 ? kn + col : krp + (col - 128));
        }
#pragma unroll
        for (int i = 0; i < 4; i++) {
            const int idx = tid + i * 256;
            vr[i] = *(const s16x8*)(KNV + (size_t)(bS + (idx >> 4)) * 4096
                                    + h * 256 + 128 + (idx & 15) * 8);
        }
    }

    for (int t = 0; t < ntiles; t++) {
#pragma unroll
        for (int i = 0; i < 6; i++)
            *(s16x8*)&k_lds[kkey][ka * 48 + i * 8] = kr[i];
#pragma unroll
        for (int i = 0; i < 4; i++) {
            const int idx = tid + i * 256;
            const int key = idx >> 4, d0 = (idx & 15) * 8;
            const int xw = (d0 >> 4) << 2;
#pragma unroll
            for (int e = 0; e < 8; e++) v_t[d0 + e][key ^ xw] = (u16)vr[i][e];
        }
        __syncthreads();

        if (t + 1 < ntiles) {
            const int nk = (t + 1) * 64;
            const u16* kn  = KNV + (size_t)(bS + nk + kkey) * 4096 + h * 256;
            const u16* krp = KR + (size_t)(bS + nk + kkey) * 64;
#pragma unroll
            for (int i = 0; i < 6; i++) {
                const int col = ka * 48 + i * 8;
                kr[i] = *(const s16x8*)(col < 128 ? kn + col : krp + (col - 128));
            }
#pragma unroll
            for (int i = 0; i < 4; i++) {
                const int idx = tid + i * 256;
                vr[i] = *(const s16x8*)(KNV + (size_t)(bS + nk + (idx >> 4)) * 4096
                                        + h * 256 + 128 + (idx & 15) * 8);
            }
        }

        const int kt0 = t * 64;

        f32x4 sa[2][4];
#pragma unroll
        for (int mb = 0; mb < 2; mb++)
#pragma unroll
            for (int f = 0; f < 4; f++) sa[mb][f] = (f32x4){0.f, 0.f, 0.f, 0.f};
#pragma unroll
        for (int kc = 0; kc < 6; kc++) {
            const int kb = kc * 32 + (lq << 2);
#pragma unroll
            for (int f = 0; f < 4; f++) {
                s16x8 kf = comb(*(const s16x4*)&k_lds[f * 16 + lr][kb],
                                *(const s16x4*)&k_lds[f * 16 + lr][kb + 16]);
                sa[0][f] = __builtin_amdgcn_mfma_f32_16x16x32_bf16(qf[0][kc], kf, sa[0][f], 0, 0, 0);
                sa[1][f] = __builtin_amdgcn_mfma_f32_16x16x32_bf16(qf[1][kc], kf, sa[1][f], 0, 0, 0);
            }
        }

#pragma unroll
        for (int mb = 0; mb < 2; mb++) {
            const int qbase = q0 + w * 32 + mb * 16 + lq * 4;
            const bool need_mask = (kt0 + 63 > qbase);
            float p[4][4];
#pragma unroll
            for (int f = 0; f < 4; f++)
#pragma unroll
                for (int r = 0; r < 4; r++) {
                    float s = sa[mb][f][r] * scale;
                    if (need_mask && (kt0 + f * 16 + lr > qbase + r)) s = -1e30f;
                    p[f][r] = s;
                }
            float nm[4], corr[4];
#pragma unroll
            for (int r = 0; r < 4; r++) {
                float tm = fmaxf(fmaxf(p[0][r], p[1][r]), fmaxf(p[2][r], p[3][r]));
#pragma unroll
                for (int off = 8; off; off >>= 1) tm = fmaxf(tm, __shfl_xor(tm, off));
                nm[r] = fmaxf(m[mb][r], tm);
                corr[r] = __expf(m[mb][r] - nm[r]);
                m[mb][r] = nm[r];
            }
#pragma unroll
            for (int f = 0; f < 4; f++)
#pragma unroll
                for (int r = 0; r < 4; r++)
                    p[f][r] = __expf(p[f][r] - nm[r]);
#pragma unroll
            for (int r = 0; r < 4; r++) {
                float ps = (p[0][r] + p[1][r]) + (p[2][r] + p[3][r]);
#pragma unroll
                for (int off = 8; off; off >>= 1) ps += __shfl_xor(ps, off);
                l[mb][r] = l[mb][r] * corr[r] + ps;
            }
#pragma unroll
            for (int d = 0; d < 8; d++)
#pragma unroll
                for (int r = 0; r < 4; r++) o_acc[mb][d][r] *= corr[r];
#pragma unroll
            for (int f = 0; f < 4; f++)
#pragma unroll
                for (int r = 0; r < 4; r++)
                    p_lds[w][mb * 16 + lq * 4 + r][f * 16 + lr] = f2b(p[f][r]);
        }
        asm volatile("s_waitcnt lgkmcnt(0)" ::: "memory");

#pragma unroll
        for (int hf = 0; hf < 2; hf++) {
            const int pc = hf * 32 + (lq << 2);
            s16x8 pa0 = comb(*(const s16x4*)&p_lds[w][lr][pc],
                             *(const s16x4*)&p_lds[w][lr][pc + 16]);
            s16x8 pa1 = comb(*(const s16x4*)&p_lds[w][16 + lr][pc],
                             *(const s16x4*)&p_lds[w][16 + lr][pc + 16]);
#pragma unroll
            for (int d = 0; d < 8; d++) {
                const int row = d * 16 + lr;
                const int xr0 = d << 2;
                s16x8 vf = comb(*(const s16x4*)&v_t[row][pc ^ xr0],
                                *(const s16x4*)&v_t[row][(pc + 16) ^ xr0]);
                o_acc[0][d] = __builtin_amdgcn_mfma_f32_16x16x32_bf16(pa0, vf, o_acc[0][d], 0, 0, 0);
                o_acc[1][d] = __builtin_amdgcn_mfma_f32_16x16x32_bf16(pa1, vf, o_acc[1][d], 0, 0, 0);
            }
        }
        __syncthreads();
    }

#pragma unroll
    for (int mb = 0; mb < 2; mb++) {
        float invl[4];
#pragma unroll
        for (int r = 0; r < 4; r++) invl[r] = 1.f / l[mb][r];
#pragma unroll
        for (int r = 0; r < 4; r++) {
            u16* op = O + (size_t)(bS + q0 + w * 32 + mb * 16 + lq * 4 + r) * 2048
                      + h * 128 + lr;
#pragma unroll
            for (int d = 0; d < 8; d++)
                op[d * 16] = f2b(o_acc[mb][d][r] * invl[r]);
        }
    }
}

// ---------------------------------------------------------------------------
extern "C" void kernel_launch(void* const* d_in, const int* in_sizes, int n_in,
                              void* d_out, int out_size, void* d_ws, size_t ws_size,
                              hipStream_t stream)
{
    const float* x    = (const float*)d_in[0];
    const float* fc   = (const float*)d_in[1];
    const float* fs   = (const float*)d_in[2];
    const float* Wqd  = (const float*)d_in[3];
    const float* bqd  = (const float*)d_in[4];
    const float* qnw  = (const float*)d_in[5];
    const float* Wqu  = (const float*)d_in[6];
    const float* bqu  = (const float*)d_in[7];
    const float* Wkvd = (const float*)d_in[8];
    const float* bkvd = (const float*)d_in[9];
    const float* kvnw = (const float*)d_in[10];
    const float* Wkvu = (const float*)d_in[11];
    const float* bkvu = (const float*)d_in[12];
    const float* Wo   = (const float*)d_in[13];
    const float* bo   = (const float*)d_in[14];

    char* ws = (char*)d_ws;
    u16* kvb     = (u16*)(ws);                 // [4096][576]
    u16* qlat    = (u16*)(ws + 4718592);       // [4096][1536]
    u16* qbuf    = (u16*)(ws + 17301504);      // [4096][3072]
    u16* krope   = (u16*)(ws + 42467328);      // [4096][64]
    u16* knv     = (u16*)(ws + 42991616);      // [4096][4096]
    u16* attn_o  = (u16*)(ws);                 // [4096][2048] reuses kvb+qlat
    u16* x_bf    = (u16*)(ws + 17301504);      // in qbuf slot
    u16* wqd_bf  = (u16*)(ws + 42991616);      // in knv slot
    u16* wkvd_bf = (u16*)(ws + 49283072);
    u16* wqu_bf  = (u16*)(ws + 51642368);
    u16* wkvu_bf = (u16*)(ws + 4718592);       // in qlat slot
    u16* wo_bf   = (u16*)(ws + 42991616);      // in knv slot

    const int M = BATCH * SEQ;  // 4096

    cvt4_k<<<2048, 256, 0, stream>>>(x, Wqd, Wkvd, Wqu, x_bf, wqd_bf, wkvd_bf, wqu_bf);
    gemm_down_k<<<dim3(17, 32), 256, 0, stream>>>(x_bf, wqd_bf, wkvd_bf, bqd, bkvd, qlat, kvb);
    rmsnorm_ip_k<<<M, 256, 0, stream>>>(qlat, qnw, 1536, 1536);
    rmsnorm_ip_k<<<M, 256, 0, stream>>>(kvb, kvnw, 512, 576);
    rope_k_k<<<(M * 32) / 256, 256, 0, stream>>>(kvb, fc, fs, krope);
    gemm_bf_k<1><<<dim3(24, 32), 256, 0, stream>>>(qlat, wqu_bf, bqu, qbuf, M, 3072, 1536, 1536);
    rope_q_k<<<(M * 16 * 32) / 256, 256, 0, stream>>>(qbuf, fc, fs);
    cvt_bf16_k<<<1024, 256, 0, stream>>>(Wkvu, wkvu_bf, 2097152 / 4);
    gemm_bf_k<1><<<dim3(32, 32), 256, 0, stream>>>(kvb, wkvu_bf, bkvu, knv, M, 4096, 512, 576);
    attn_k<<<512, 256, 0, stream>>>(qbuf, knv, krope, attn_o);
    cvt_bf16_k<<<1024, 256, 0, stream>>>(Wo, wo_bf, 4194304 / 4);
    gemm_bf_k<0><<<dim3(16, 32), 256, 0, stream>>>(attn_o, wo_bf, bo, (float*)d_out, M, 2048, 2048, 2048);
}

// Round 16
// 403.828 us; speedup vs baseline: 1.2284x; 1.1656x over previous
//
#include <hip/hip_runtime.h>

typedef unsigned short u16;
typedef short s16x8 __attribute__((ext_vector_type(8)));
typedef short s16x4 __attribute__((ext_vector_type(4)));
typedef float f32x4 __attribute__((ext_vector_type(4)));

#define SEQ   2048
#define BATCH 2
#define NHEAD 16

__device__ __forceinline__ float b2f(u16 u) {
    unsigned x = ((unsigned)u) << 16;
    return __builtin_bit_cast(float, x);
}
__device__ __forceinline__ u16 f2b(float f) {
    unsigned x = __builtin_bit_cast(unsigned, f);
    unsigned r = (x + 0x7fffu + ((x >> 16) & 1u)) >> 16;
    return (u16)r;
}
__device__ __forceinline__ s16x8 comb(s16x4 lo, s16x4 hi) {
    return __builtin_shufflevector(lo, hi, 0, 1, 2, 3, 4, 5, 6, 7);
}
__device__ __forceinline__ void gload16(const void* g, void* l) {
    __builtin_amdgcn_global_load_lds(
        (const __attribute__((address_space(1))) void*)g,
        (__attribute__((address_space(3))) void*)l, 16, 0, 0);
}

// ---------------------------------------------------------------------------
// Fused f32->bf16 convert for 4 regions (x, Wqd, Wkvd, Wqu).
// ---------------------------------------------------------------------------
__global__ __launch_bounds__(256) void cvt4_k(
    const float* __restrict__ x, const float* __restrict__ wqd,
    const float* __restrict__ wkvd, const float* __restrict__ wqu,
    u16* __restrict__ xb, u16* __restrict__ wqdb,
    u16* __restrict__ wkvdb, u16* __restrict__ wqub)
{
    const int total = 4358144;
    int i = blockIdx.x * 256 + threadIdx.x;
    const int stride = gridDim.x * 256;
    for (; i < total; i += stride) {
        const float4* src; ushort4* dst; int off;
        if (i < 2097152)      { src = (const float4*)x;    dst = (ushort4*)xb;    off = i; }
        else if (i < 2883584) { src = (const float4*)wqd;  dst = (ushort4*)wqdb;  off = i - 2097152; }
        else if (i < 3178496) { src = (const float4*)wkvd; dst = (ushort4*)wkvdb; off = i - 2883584; }
        else                  { src = (const float4*)wqu;  dst = (ushort4*)wqub;  off = i - 3178496; }
        float4 v = src[off];
        ushort4 o = { f2b(v.x), f2b(v.y), f2b(v.z), f2b(v.w) };
        dst[off] = o;
    }
}

__global__ __launch_bounds__(256) void cvt_bf16_k(
    const float* __restrict__ in, u16* __restrict__ out, int n4)
{
    int i = blockIdx.x * 256 + threadIdx.x;
    const int stride = gridDim.x * 256;
    for (; i < n4; i += stride) {
        float4 v = ((const float4*)in)[i];
        ushort4 o = { f2b(v.x), f2b(v.y), f2b(v.z), f2b(v.w) };
        ((ushort4*)out)[i] = o;
    }
}

// ---------------------------------------------------------------------------
// m97-style MFMA GEMM: C[M,N] = A[M,K](bf16) @ W[N,K](bf16)^T + bias[N](f32)
// ---------------------------------------------------------------------------
template <int OUT_BF16>
__global__ __launch_bounds__(256) void gemm_bf_k(
    const u16* __restrict__ A, const u16* __restrict__ W,
    const float* __restrict__ bias, void* __restrict__ Cout,
    int M, int N, int K, int lda)
{
    __shared__ u16 lsA[128 * 64];
    __shared__ u16 lsB[128 * 64];
    const int tid  = threadIdx.x;
    const int lane = tid & 63;
    const int w    = tid >> 6;
    const int wm   = w >> 1, wn = w & 1;
    const int row0 = blockIdx.y * 128;
    const int col0 = blockIdx.x * 128;
    const int lr8  = lane >> 3;
    const int lc8  = (lane & 7) * 8;

    f32x4 acc[4][4];
#pragma unroll
    for (int i = 0; i < 4; i++)
#pragma unroll
        for (int j = 0; j < 4; j++) acc[i][j] = (f32x4){0.f, 0.f, 0.f, 0.f};

    for (int kt = 0; kt < K; kt += 64) {
#pragma unroll
        for (int t = 0; t < 4; t++) {
            const int r = w * 32 + t * 8;
            gload16(A + (size_t)(row0 + r + lr8) * lda + kt + lc8, &lsA[r * 64]);
            int rw = col0 + r + lr8; if (rw >= N) rw = N - 1;
            gload16(W + (size_t)rw * K + kt + lc8, &lsB[r * 64]);
        }
        __syncthreads();
#pragma unroll
        for (int ks = 0; ks < 2; ks++) {
            const int ko = ks * 32 + (lane >> 4) * 8;
            s16x8 af[4], bfr[4];
#pragma unroll
            for (int i = 0; i < 4; i++) {
                af[i]  = *(const s16x8*)&lsA[(wm * 64 + i * 16 + (lane & 15)) * 64 + ko];
                bfr[i] = *(const s16x8*)&lsB[(wn * 64 + i * 16 + (lane & 15)) * 64 + ko];
            }
#pragma unroll
            for (int mf = 0; mf < 4; mf++)
#pragma unroll
                for (int nf = 0; nf < 4; nf++)
                    acc[mf][nf] = __builtin_amdgcn_mfma_f32_16x16x32_bf16(
                        af[mf], bfr[nf], acc[mf][nf], 0, 0, 0);
        }
        __syncthreads();
    }

    const int rb = row0 + wm * 64 + ((lane >> 4) << 2);
    const int cb = col0 + wn * 64 + (lane & 15);
#pragma unroll
    for (int nf = 0; nf < 4; nf++) {
        const int col = cb + nf * 16;
        if (col < N) {
            const float bv = bias[col];
#pragma unroll
            for (int mf = 0; mf < 4; mf++)
#pragma unroll
                for (int r = 0; r < 4; r++) {
                    const int row = rb + mf * 16 + r;
                    float v = acc[mf][nf][r] + bv;
                    if (OUT_BF16) ((u16*)Cout)[(size_t)row * N + col] = f2b(v);
                    else          ((float*)Cout)[(size_t)row * N + col] = v;
                }
        }
    }
}

// ---------------------------------------------------------------------------
// Merged down-projection GEMM (virtual N = 2112: qlat cols + kvb cols).
// ---------------------------------------------------------------------------
__global__ __launch_bounds__(256) void gemm_down_k(
    const u16* __restrict__ A, const u16* __restrict__ W0,
    const u16* __restrict__ W1, const float* __restrict__ b0,
    const float* __restrict__ b1, u16* __restrict__ C0, u16* __restrict__ C1)
{
    __shared__ u16 lsA[128 * 64];
    __shared__ u16 lsB[128 * 64];
    const int tid  = threadIdx.x;
    const int lane = tid & 63;
    const int w    = tid >> 6;
    const int wm   = w >> 1, wn = w & 1;
    const int row0 = blockIdx.y * 128;
    const int col0 = blockIdx.x * 128;
    const int lr8  = lane >> 3;
    const int lc8  = (lane & 7) * 8;
    const bool in1 = (col0 >= 1536);
    const u16* Wm  = in1 ? W1 : W0;
    const int wbase = in1 ? col0 - 1536 : col0;
    const int wmax  = in1 ? 575 : 1535;

    f32x4 acc[4][4];
#pragma unroll
    for (int i = 0; i < 4; i++)
#pragma unroll
        for (int j = 0; j < 4; j++) acc[i][j] = (f32x4){0.f, 0.f, 0.f, 0.f};

    for (int kt = 0; kt < 2048; kt += 64) {
#pragma unroll
        for (int t = 0; t < 4; t++) {
            const int r = w * 32 + t * 8;
            gload16(A + (size_t)(row0 + r + lr8) * 2048 + kt + lc8, &lsA[r * 64]);
            int rw = wbase + r + lr8; if (rw > wmax) rw = wmax;
            gload16(Wm + (size_t)rw * 2048 + kt + lc8, &lsB[r * 64]);
        }
        __syncthreads();
#pragma unroll
        for (int ks = 0; ks < 2; ks++) {
            const int ko = ks * 32 + (lane >> 4) * 8;
            s16x8 af[4], bfr[4];
#pragma unroll
            for (int i = 0; i < 4; i++) {
                af[i]  = *(const s16x8*)&lsA[(wm * 64 + i * 16 + (lane & 15)) * 64 + ko];
                bfr[i] = *(const s16x8*)&lsB[(wn * 64 + i * 16 + (lane & 15)) * 64 + ko];
            }
#pragma unroll
            for (int mf = 0; mf < 4; mf++)
#pragma unroll
                for (int nf = 0; nf < 4; nf++)
                    acc[mf][nf] = __builtin_amdgcn_mfma_f32_16x16x32_bf16(
                        af[mf], bfr[nf], acc[mf][nf], 0, 0, 0);
        }
        __syncthreads();
    }

    const int rb = row0 + wm * 64 + ((lane >> 4) << 2);
    const int cb = col0 + wn * 64 + (lane & 15);
#pragma unroll
    for (int nf = 0; nf < 4; nf++) {
        const int col = cb + nf * 16;
        if (col < 2112) {
            const bool c1 = (col >= 1536);
            const float bv = c1 ? b1[col - 1536] : b0[col];
#pragma unroll
            for (int mf = 0; mf < 4; mf++)
#pragma unroll
                for (int r = 0; r < 4; r++) {
                    const int row = rb + mf * 16 + r;
                    float v = acc[mf][nf][r] + bv;
                    if (c1) C1[(size_t)row * 576 + col - 1536] = f2b(v);
                    else    C0[(size_t)row * 1536 + col] = f2b(v);
                }
        }
    }
}

// ---------------------------------------------------------------------------
// Merged RMSNorm (qlat + kvb) + rope_k. Blocks 0..4095: qlat row; 4096..8191:
// kvb row (cols 0..511) + rope on raw cols 512..575 -> krope.
// ---------------------------------------------------------------------------
__global__ __launch_bounds__(256) void norm_rope_k(
    u16* __restrict__ qlat, u16* __restrict__ kvb,
    const float* __restrict__ qnw, const float* __restrict__ kvnw,
    const float* __restrict__ fc, const float* __restrict__ fs,
    u16* __restrict__ krope)
{
    const int bid = blockIdx.x;
    const int row = bid & 4095;
    const bool isq = bid < 4096;
    u16* xr = isq ? qlat + (size_t)row * 1536 : kvb + (size_t)row * 576;
    const int cols = isq ? 1536 : 512;
    const float* wv = isq ? qnw : kvnw;

    if (!isq && threadIdx.x < 32) {   // rope on raw (un-normed) cols 512..575
        const int i = threadIdx.x;
        const int s = row & (SEQ - 1);
        const u16* src = kvb + (size_t)row * 576 + 512 + 2 * i;
        const float xr0 = b2f(src[0]), xi0 = b2f(src[1]);
        const float c = fc[s * 32 + i], sn = fs[s * 32 + i];
        ushort2 o;
        o.x = f2b(xr0 * c - xi0 * sn);
        o.y = f2b(xr0 * sn + xi0 * c);
        *((ushort2*)(krope + (size_t)row * 64) + i) = o;
    }

    float ss = 0.f;
    for (int c = threadIdx.x; c < cols; c += 256) { float v = b2f(xr[c]); ss += v * v; }
#pragma unroll
    for (int off = 32; off; off >>= 1) ss += __shfl_xor(ss, off);
    __shared__ float red[4];
    if ((threadIdx.x & 63) == 0) red[threadIdx.x >> 6] = ss;
    __syncthreads();
    const float tot = red[0] + red[1] + red[2] + red[3];
    const float inv = rsqrtf(tot / (float)cols + 1.1920929e-7f);
    for (int c = threadIdx.x; c < cols; c += 256)
        xr[c] = f2b(b2f(xr[c]) * inv * wv[c]);
}

// ---------------------------------------------------------------------------
// RoPE on Q
// ---------------------------------------------------------------------------
__global__ __launch_bounds__(256) void rope_q_k(
    u16* __restrict__ qb, const float* __restrict__ fc, const float* __restrict__ fs)
{
    const int idx = blockIdx.x * 256 + threadIdx.x;
    const int i = idx & 31;
    const int h = (idx >> 5) & 15;
    const int row = idx >> 9;
    const int s = row & (SEQ - 1);
    ushort2* p = (ushort2*)(qb + (size_t)row * 3072 + h * 192 + 128) + i;
    ushort2 v = *p;
    const float xr = b2f(v.x), xi = b2f(v.y);
    const float c = fc[s * 32 + i], sn = fs[s * 32 + i];
    ushort2 o;
    o.x = f2b(xr * c - xi * sn);
    o.y = f2b(xr * sn + xi * c);
    *p = o;
}

// ---------------------------------------------------------------------------
// MFMA flash attention v6: swapped QK^T (S^T in C layout) -> softmax fully
// in-register (2 shuffles/row-stat), P packs directly into PV B-operand,
// PV computes O^T. No p_lds. Defer-max rescale (THR=8, wave-uniform).
// Block = (b,h,128 q-rows); 4 waves x 32 rows; KVBLK=64; reg prefetch.
// ---------------------------------------------------------------------------
__global__ __launch_bounds__(256, 2) void attn_k(
    const u16* __restrict__ Q, const u16* __restrict__ KNV,
    const u16* __restrict__ KR, u16* __restrict__ O)
{
    __shared__ u16 k_lds[64][200];
    __shared__ u16 v_t[128][68];

    const int tid  = threadIdx.x;
    const int lane = tid & 63;
    const int w    = tid >> 6;
    const int lr   = lane & 15;
    const int lq   = lane >> 4;

    const int bid = blockIdx.x;
    const int qt  = (bid < 256) ? (15 - (bid >> 5)) : ((bid - 256) >> 5);
    const int bh  = bid & 31;
    const int h   = bh & 15;
    const int b   = bh >> 4;
    const int q0  = qt * 128;
    const int bS  = b * SEQ;

    // Q fragments (operand layout): 2 m-blocks x 6 k-chunks
    s16x8 qf[2][6];
#pragma unroll
    for (int mb = 0; mb < 2; mb++) {
        const u16* qp = Q + (size_t)(bS + q0 + w * 32 + mb * 16 + lr) * 3072
                        + h * 192 + (lq << 2);
#pragma unroll
        for (int kc = 0; kc < 6; kc++)
            qf[mb][kc] = comb(*(const s16x4*)(qp + kc * 32),
                              *(const s16x4*)(qp + kc * 32 + 16));
    }

    // O^T accumulators: o_acc[mb][df][r] = O[qrow=lr][d = df*16 + lq*4 + r]
    f32x4 o_acc[2][8];
#pragma unroll
    for (int mb = 0; mb < 2; mb++)
#pragma unroll
        for (int d = 0; d < 8; d++) o_acc[mb][d] = (f32x4){0.f, 0.f, 0.f, 0.f};
    float m_run[2] = { -1e30f, -1e30f };
    float l_run[2] = { 0.f, 0.f };

    const float scale = 0.07216878364870323f;  // 192^-0.5
    const int ntiles = (q0 + 128) / 64;

    s16x8 kr[6], vr[4];
    const int kkey = tid >> 2;
    const int ka   = tid & 3;

    {
        const u16* kn  = KNV + (size_t)(bS + kkey) * 4096 + h * 256;
        const u16* krp = KR + (size_t)(bS + kkey) * 64;
#pragma unroll
        for (int i = 0; i < 6; i++) {
            const int col = ka * 48 + i * 8;
            kr[i] = *(const s16x8*)(col < 128 ? kn + col : krp + (col - 128));
        }
#pragma unroll
        for (int i = 0; i < 4; i++) {
            const int idx = tid + i * 256;
            vr[i] = *(const s16x8*)(KNV + (size_t)(bS + (idx >> 4)) * 4096
                                    + h * 256 + 128 + (idx & 15) * 8);
        }
    }

    for (int t = 0; t < ntiles; t++) {
#pragma unroll
        for (int i = 0; i < 6; i++)
            *(s16x8*)&k_lds[kkey][ka * 48 + i * 8] = kr[i];
#pragma unroll
        for (int i = 0; i < 4; i++) {
            const int idx = tid + i * 256;
            const int key = idx >> 4, d0 = (idx & 15) * 8;
            const int xw = (d0 >> 4) << 2;
#pragma unroll
            for (int e = 0; e < 8; e++) v_t[d0 + e][key ^ xw] = (u16)vr[i][e];
        }
        __syncthreads();

        if (t + 1 < ntiles) {
            const int nk = (t + 1) * 64;
            const u16* kn  = KNV + (size_t)(bS + nk + kkey) * 4096 + h * 256;
            const u16* krp = KR + (size_t)(bS + nk + kkey) * 64;
#pragma unroll
            for (int i = 0; i < 6; i++) {
                const int col = ka * 48 + i * 8;
                kr[i] = *(const s16x8*)(col < 128 ? kn + col : krp + (col - 128));
            }
#pragma unroll
            for (int i = 0; i < 4; i++) {
                const int idx = tid + i * 256;
                vr[i] = *(const s16x8*)(KNV + (size_t)(bS + nk + (idx >> 4)) * 4096
                                        + h * 256 + 128 + (idx & 15) * 8);
            }
        }

        const int kt0 = t * 64;

        // QK^T swapped: sa[mb][f] = S^T frag -> lane holds key=(lq*4+r), qrow=lr
        f32x4 sa[2][4];
#pragma unroll
        for (int mb = 0; mb < 2; mb++)
#pragma unroll
            for (int f = 0; f < 4; f++) sa[mb][f] = (f32x4){0.f, 0.f, 0.f, 0.f};
#pragma unroll
        for (int kc = 0; kc < 6; kc++) {
            const int kb = kc * 32 + (lq << 2);
#pragma unroll
            for (int f = 0; f < 4; f++) {
                s16x8 kf = comb(*(const s16x4*)&k_lds[f * 16 + lr][kb],
                                *(const s16x4*)&k_lds[f * 16 + lr][kb + 16]);
                sa[0][f] = __builtin_amdgcn_mfma_f32_16x16x32_bf16(kf, qf[0][kc], sa[0][f], 0, 0, 0);
                sa[1][f] = __builtin_amdgcn_mfma_f32_16x16x32_bf16(kf, qf[1][kc], sa[1][f], 0, 0, 0);
            }
        }

        // in-register online softmax + pack P into PV B-operands
        s16x8 pb[2][2];
#pragma unroll
        for (int mb = 0; mb < 2; mb++) {
            const int qrow = q0 + w * 32 + mb * 16 + lr;
            const bool need_mask = (kt0 + 63 > qrow);
            float p[4][4];
#pragma unroll
            for (int f = 0; f < 4; f++)
#pragma unroll
                for (int r = 0; r < 4; r++) {
                    float s = sa[mb][f][r] * scale;
                    if (need_mask && (kt0 + f * 16 + lq * 4 + r > qrow)) s = -1e30f;
                    p[f][r] = s;
                }
            // tile max over 16 in-reg + 2 shuffles (across lq groups)
            float tm = p[0][0];
#pragma unroll
            for (int f = 0; f < 4; f++)
#pragma unroll
                for (int r = 0; r < 4; r++) tm = fmaxf(tm, p[f][r]);
            tm = fmaxf(tm, __shfl_xor(tm, 16));
            tm = fmaxf(tm, __shfl_xor(tm, 32));

            const float mo = m_run[mb];
            const bool keep = __all(tm <= mo + 8.f);   // defer-max (T13)
            float corr = 1.f;
            if (!keep) {
                const float nm = fmaxf(mo, tm);
                corr = __expf(mo - nm);
                m_run[mb] = nm;
            }
            const float mb_base = m_run[mb];
#pragma unroll
            for (int f = 0; f < 4; f++)
#pragma unroll
                for (int r = 0; r < 4; r++)
                    p[f][r] = __expf(p[f][r] - mb_base);
            float ps = 0.f;
#pragma unroll
            for (int f = 0; f < 4; f++)
#pragma unroll
                for (int r = 0; r < 4; r++) ps += p[f][r];
            ps += __shfl_xor(ps, 16);
            ps += __shfl_xor(ps, 32);
            l_run[mb] = l_run[mb] * corr + ps;
            if (!keep) {
#pragma unroll
                for (int d = 0; d < 8; d++)
#pragma unroll
                    for (int r = 0; r < 4; r++) o_acc[mb][d][r] *= corr;
            }
            // pack: pb[hf] slot j <- P[key = hf*32 + lq*4 + (j&3) + 16*(j>>2)]
#pragma unroll
            for (int hf = 0; hf < 2; hf++) {
                s16x8 v;
#pragma unroll
                for (int j = 0; j < 8; j++)
                    v[j] = (short)f2b(p[hf * 2 + (j >> 2)][j & 3]);
                pb[mb][hf] = v;
            }
        }

        // PV as O^T: o_acc[mb][df] = mfma(vf, pb) ; vf reads shared across mb
#pragma unroll
        for (int hf = 0; hf < 2; hf++) {
            const int pc = hf * 32 + (lq << 2);
#pragma unroll
            for (int df = 0; df < 8; df++) {
                const int row = df * 16 + lr;
                const int xr0 = df << 2;
                s16x8 vf = comb(*(const s16x4*)&v_t[row][pc ^ xr0],
                                *(const s16x4*)&v_t[row][(pc + 16) ^ xr0]);
                o_acc[0][df] = __builtin_amdgcn_mfma_f32_16x16x32_bf16(vf, pb[0][hf], o_acc[0][df], 0, 0, 0);
                o_acc[1][df] = __builtin_amdgcn_mfma_f32_16x16x32_bf16(vf, pb[1][hf], o_acc[1][df], 0, 0, 0);
            }
        }
        __syncthreads();
    }

    // epilogue: O[qrow][h*128 + df*16 + lq*4 + r]
#pragma unroll
    for (int mb = 0; mb < 2; mb++) {
        const float invl = 1.f / l_run[mb];
        u16* op = O + (size_t)(bS + q0 + w * 32 + mb * 16 + lr) * 2048 + h * 128 + lq * 4;
#pragma unroll
        for (int df = 0; df < 8; df++) {
            ushort4 ov = { f2b(o_acc[mb][df][0] * invl), f2b(o_acc[mb][df][1] * invl),
                           f2b(o_acc[mb][df][2] * invl), f2b(o_acc[mb][df][3] * invl) };
            *(ushort4*)(op + df * 16) = ov;
        }
    }
}

// ---------------------------------------------------------------------------
extern "C" void kernel_launch(void* const* d_in, const int* in_sizes, int n_in,
                              void* d_out, int out_size, void* d_ws, size_t ws_size,
                              hipStream_t stream)
{
    const float* x    = (const float*)d_in[0];
    const float* fc   = (const float*)d_in[1];
    const float* fs   = (const float*)d_in[2];
    const float* Wqd  = (const float*)d_in[3];
    const float* bqd  = (const float*)d_in[4];
    const float* qnw  = (const float*)d_in[5];
    const float* Wqu  = (const float*)d_in[6];
    const float* bqu  = (const float*)d_in[7];
    const float* Wkvd = (const float*)d_in[8];
    const float* bkvd = (const float*)d_in[9];
    const float* kvnw = (const float*)d_in[10];
    const float* Wkvu = (const float*)d_in[11];
    const float* bkvu = (const float*)d_in[12];
    const float* Wo   = (const float*)d_in[13];
    const float* bo   = (const float*)d_in[14];

    char* ws = (char*)d_ws;
    u16* kvb     = (u16*)(ws);                 // [4096][576]
    u16* qlat    = (u16*)(ws + 4718592);       // [4096][1536]
    u16* qbuf    = (u16*)(ws + 17301504);      // [4096][3072]
    u16* krope   = (u16*)(ws + 42467328);      // [4096][64]
    u16* knv     = (u16*)(ws + 42991616);      // [4096][4096]
    u16* attn_o  = (u16*)(ws);                 // [4096][2048] reuses kvb+qlat
    u16* x_bf    = (u16*)(ws + 17301504);      // in qbuf slot
    u16* wqd_bf  = (u16*)(ws + 42991616);      // in knv slot
    u16* wkvd_bf = (u16*)(ws + 49283072);
    u16* wqu_bf  = (u16*)(ws + 51642368);
    u16* wkvu_bf = (u16*)(ws + 4718592);       // in qlat slot
    u16* wo_bf   = (u16*)(ws + 42991616);      // in knv slot

    const int M = BATCH * SEQ;  // 4096

    cvt4_k<<<2048, 256, 0, stream>>>(x, Wqd, Wkvd, Wqu, x_bf, wqd_bf, wkvd_bf, wqu_bf);
    gemm_down_k<<<dim3(17, 32), 256, 0, stream>>>(x_bf, wqd_bf, wkvd_bf, bqd, bkvd, qlat, kvb);
    norm_rope_k<<<8192, 256, 0, stream>>>(qlat, kvb, qnw, kvnw, fc, fs, krope);
    gemm_bf_k<1><<<dim3(24, 32), 256, 0, stream>>>(qlat, wqu_bf, bqu, qbuf, M, 3072, 1536, 1536);
    rope_q_k<<<(M * 16 * 32) / 256, 256, 0, stream>>>(qbuf, fc, fs);
    cvt_bf16_k<<<1024, 256, 0, stream>>>(Wkvu, wkvu_bf, 2097152 / 4);
    gemm_bf_k<1><<<dim3(32, 32), 256, 0, stream>>>(kvb, wkvu_bf, bkvu, knv, M, 4096, 512, 576);
    attn_k<<<512, 256, 0, stream>>>(qbuf, knv, krope, attn_o);
    cvt_bf16_k<<<1024, 256, 0, stream>>>(Wo, wo_bf, 4194304 / 4);
    gemm_bf_k<0><<<dim3(16, 32), 256, 0, stream>>>(attn_o, wo_bf, bo, (float*)d_out, M, 2048, 2048, 2048);
}